// Round 3
// baseline (739.436 us; speedup 1.0000x reference)
//
#include <hip/hip_runtime.h>

#define C 64

typedef float fx4 __attribute__((ext_vector_type(4)));

// ---------------------------------------------------------------------------
// K1: FUSED dot + histogram/rank.
//  dot part  : d[i] = dot(x[i,:], lin_w). Four nodes per wave: 16 lanes/node,
//              float4 each (16 lanes * 16B = 256B row) -> wave reads 1024B
//              contiguous. Reduce via 4 xor-shuffles within 16-lane group.
//  hist part : threads with gtid < n handle edge e = gtid:
//              rank[e] = atomicAdd(&count[dst], 1).
//  NOTE: x flows through L2/L3 here; gather re-reads it — keep cached.
// ---------------------------------------------------------------------------
__global__ void dot_hist_kernel(const float4* __restrict__ x4,
                                const float4* __restrict__ w4,
                                const int* __restrict__ ei,
                                float* __restrict__ d,
                                int* __restrict__ count,
                                int* __restrict__ rank,
                                int n) {
    int gtid = blockIdx.x * blockDim.x + threadIdx.x;

    if (gtid < n) {
        int t = ei[n + gtid];
        rank[gtid] = atomicAdd(&count[t], 1);
    }

    int wave = gtid >> 6;
    int lane = threadIdx.x & 63;
    int sub  = lane >> 4;          // which node within the wave (0..3)
    int sl   = lane & 15;          // lane within node group
    int node = wave * 4 + sub;
    if (node >= n) return;
    float4 v = x4[(size_t)node * 16 + sl];
    float4 w = w4[sl];
    float t = v.x * w.x + v.y * w.y + v.z * w.z + v.w * w.w;
    t += __shfl_xor(t, 8, 64);
    t += __shfl_xor(t, 4, 64);
    t += __shfl_xor(t, 2, 64);
    t += __shfl_xor(t, 1, 64);
    if (sl == 0) d[node] = t;
}

// ---------------------------------------------------------------------------
// K2: FUSED learned-scatter + scan1.
//  scatter : learned[t] += d[s]-d[t]+lin_b   (t >= first only; learned was
//            zero-initialized by the memset; the self-loop lin_b and the
//            per-node base are added in reorder instead).
//  scan1   : block-local exclusive scan of count[] -> off[], block sums to
//            partial[].
// ---------------------------------------------------------------------------
__global__ void scatter_scan1_kernel(const int* __restrict__ ei,
                                     const float* __restrict__ d,
                                     const float* __restrict__ lin_b,
                                     float* __restrict__ learned,
                                     const int* __restrict__ count,
                                     int* __restrict__ off,
                                     int* __restrict__ partial,
                                     int n, int first) {
    __shared__ int sh[256];
    int tid = threadIdx.x;
    int gid = blockIdx.x * 256 + tid;

    // scatter (issue first: atomics drain while the scan runs)
    int t = ei[n + gid];
    if (t >= first) {
        int s = ei[gid];
        atomicAdd(&learned[t], d[s] - d[t] + lin_b[0]);
    }

    // scan1
    int v = count[gid];
    sh[tid] = v;
    __syncthreads();
    for (int o = 1; o < 256; o <<= 1) {
        int tt = (tid >= o) ? sh[tid - o] : 0;
        __syncthreads();
        sh[tid] += tt;
        __syncthreads();
    }
    off[gid] = sh[tid] - v;
    if (tid == 255) partial[blockIdx.x] = sh[255];
}

__global__ void scan2_kernel(int* __restrict__ partial, int nb) {
    __shared__ int sh[256];
    int tid = threadIdx.x;
    int chunk = nb / 256;
    int base = tid * chunk;
    int sum = 0;
    for (int k = 0; k < chunk; ++k) sum += partial[base + k];
    sh[tid] = sum;
    __syncthreads();
    for (int o = 1; o < 256; o <<= 1) {
        int t = (tid >= o) ? sh[tid - o] : 0;
        __syncthreads();
        sh[tid] += t;
        __syncthreads();
    }
    int running = sh[tid] - sum;
    for (int k = 0; k < chunk; ++k) {
        int v = partial[base + k];
        partial[base + k] = running;
        running += v;
    }
}

// ---------------------------------------------------------------------------
// K3: reorder edges into CSR buckets (atomic-free; uses captured rank).
//   score[e] = w1                                  , e <  first
//            = (w2|w3) + lin_b + learned[e]        , e >= first
//   final offset = off[t] + partial[t>>8]  (scan3 folded in here)
// ---------------------------------------------------------------------------
__global__ void reorder_kernel(const int* __restrict__ ei,
                               const float* __restrict__ learned,
                               const int* __restrict__ off,
                               const int* __restrict__ partial,
                               const int* __restrict__ rank,
                               int2* __restrict__ srcscore,
                               const float* __restrict__ lin_b,
                               const float* __restrict__ w1,
                               const float* __restrict__ w2,
                               const float* __restrict__ w3,
                               int n, int first) {
    int e = blockIdx.x * blockDim.x + threadIdx.x;
    if (e >= n) return;
    float score;
    if (e < first) {
        score = w1[0];
    } else {
        float base = (((e - first) & 1) == 0) ? w2[0] : w3[0];
        score = base + lin_b[0] + learned[e];
    }
    int s = ei[e];
    int t = ei[n + e];
    int pos = off[t] + partial[t >> 8] + rank[e];
    srcscore[pos] = make_int2(s, __float_as_int(score));
}

// ---------------------------------------------------------------------------
// K4: gather — ONE node per wave, FOUR edges in flight per trip.
//   lanes [16*k, 16*k+15] serve edge slot k: each lane loads one float4 of
//   x[src_k]. All 4 edge rows (up to 1024 B) issue in a single VMEM
//   instruction -> 4x memory-level parallelism vs the serial per-edge loop,
//   and degree divergence is gone (loop trips = ceil(deg/4), uniform across
//   the wave; mean degree 1 -> 1 trip for ~99% of nodes).
//   Cross-subgroup reduce: 2 shfl_xor steps (16, 32); lanes 0-15 store.
//   srcscore[j] read by 16 same-address lanes -> hardware broadcast.
//   out stores NONTEMPORAL: keep x L3-resident for the random row reads.
// ---------------------------------------------------------------------------
__global__ void gather_kernel(const float4* __restrict__ x4,
                              const int* __restrict__ off,
                              const int* __restrict__ partial,
                              const int2* __restrict__ srcscore,
                              float4* __restrict__ out4, int n) {
    int gtid = blockIdx.x * blockDim.x + threadIdx.x;
    int node = gtid >> 6;          // one node per wave
    int lane = threadIdx.x & 63;
    int sub  = lane >> 4;          // edge slot within trip (0..3)
    int sl   = lane & 15;          // float4 index within row
    if (node >= n) return;
    int beg = off[node] + partial[node >> 8];
    int end = (node + 1 < n) ? (off[node + 1] + partial[(node + 1) >> 8]) : n;
    float4 acc = make_float4(0.f, 0.f, 0.f, 0.f);
    for (int j0 = beg; j0 < end; j0 += 4) {
        int j = j0 + sub;
        if (j < end) {
            int2 p = srcscore[j];              // same addr across 16 lanes
            float s = __int_as_float(p.y);
            float4 v = x4[(size_t)p.x * 16 + sl];
            acc.x += v.x * s;
            acc.y += v.y * s;
            acc.z += v.z * s;
            acc.w += v.w * s;
        }
    }
    // reduce over the 4 edge slots
    acc.x += __shfl_xor(acc.x, 16, 64);
    acc.y += __shfl_xor(acc.y, 16, 64);
    acc.z += __shfl_xor(acc.z, 16, 64);
    acc.w += __shfl_xor(acc.w, 16, 64);
    acc.x += __shfl_xor(acc.x, 32, 64);
    acc.y += __shfl_xor(acc.y, 32, 64);
    acc.z += __shfl_xor(acc.z, 32, 64);
    acc.w += __shfl_xor(acc.w, 32, 64);
    if (sub == 0) {
        acc.x = fmaxf(acc.x, 0.f);
        acc.y = fmaxf(acc.y, 0.f);
        acc.z = fmaxf(acc.z, 0.f);
        acc.w = fmaxf(acc.w, 0.f);
        fx4 av;
        av.x = acc.x; av.y = acc.y; av.z = acc.z; av.w = acc.w;
        __builtin_nontemporal_store(av, (fx4*)&out4[(size_t)node * 16 + sl]);
    }
}

extern "C" void kernel_launch(void* const* d_in, const int* in_sizes, int n_in,
                              void* d_out, int out_size, void* d_ws, size_t ws_size,
                              hipStream_t stream) {
    const float* x     = (const float*)d_in[0];   // [N, 64]
    const float* lin_w = (const float*)d_in[1];   // [1, 64]
    const float* lin_b = (const float*)d_in[2];   // [1]
    const float* w1    = (const float*)d_in[3];
    const float* w2    = (const float*)d_in[4];
    const float* w3    = (const float*)d_in[5];
    const int*   ei    = (const int*)d_in[6];     // [2, N]
    float* out = (float*)d_out;                   // [N, 64]

    const int n = in_sizes[0] / C;                // nodes == edges (1048576)
    const int first = n / 3;
    const int nb = n / 256;                       // 4096

    // workspace: 7n ints/floats + nb   (learned and count adjacent -> one memset)
    float* d_dot    = (float*)d_ws;               // n
    float* learned  = d_dot + n;                  // n  (zero = bits 0 for f32)
    int*   count    = (int*)(learned + n);        // n
    int*   off      = count + n;                  // n
    int*   rank     = off + n;                    // n
    int2*  srcscore = (int2*)(rank + n);          // n int2
    int*   partial  = (int*)(srcscore + n);       // nb

    hipMemsetAsync(learned, 0, (size_t)2 * n * sizeof(int), stream);

    // K1: dot (n/4 waves -> n*16 threads) + count/rank hist (first n threads)
    dot_hist_kernel<<<dim3(n / 16), dim3(256), 0, stream>>>(
        (const float4*)x, (const float4*)lin_w, ei, d_dot, count, rank, n);
    // K2: learned scatter + scan1
    scatter_scan1_kernel<<<dim3(nb), dim3(256), 0, stream>>>(
        ei, d_dot, lin_b, learned, count, off, partial, n, first);
    scan2_kernel<<<dim3(1), dim3(256), 0, stream>>>(partial, nb);
    reorder_kernel<<<dim3(nb), dim3(256), 0, stream>>>(ei, learned, off, partial,
                                                       rank, srcscore, lin_b,
                                                       w1, w2, w3, n, first);
    // one wave per node -> n waves -> n*64 threads -> n/4 blocks
    gather_kernel<<<dim3(n / 4), dim3(256), 0, stream>>>(
        (const float4*)x, off, partial, srcscore, (float4*)out, n);
}

// Round 5
// 657.700 us; speedup vs baseline: 1.1243x; 1.1243x over previous
//
#include <hip/hip_runtime.h>

#define C 64

typedef float fx4 __attribute__((ext_vector_type(4)));

// ---------------------------------------------------------------------------
// K1: FUSED dot + degree histogram.
//  dot part  : d[i] = dot(x[i,:], lin_w). Four nodes per wave: 16 lanes/node,
//              float4 each -> wave reads 1024B contiguous. Reduce via 4
//              xor-shuffles within the 16-lane group.
//  hist part : threads with gtid < n handle edge e = gtid:
//              count[dst]++  (fire-and-forget atomic — no return needed,
//              rank capture eliminated; reorder claims positions itself).
//  NOTE: x flows through L2/L3 here; gather re-reads it — keep cached.
// ---------------------------------------------------------------------------
__global__ void dot_hist_kernel(const float4* __restrict__ x4,
                                const float4* __restrict__ w4,
                                const int* __restrict__ ei,
                                float* __restrict__ d,
                                int* __restrict__ count,
                                int n) {
    int gtid = blockIdx.x * blockDim.x + threadIdx.x;

    if (gtid < n) {
        int t = ei[n + gtid];
        atomicAdd(&count[t], 1);           // no return-value dependency
    }

    int wave = gtid >> 6;
    int lane = threadIdx.x & 63;
    int sub  = lane >> 4;          // which node within the wave (0..3)
    int sl   = lane & 15;          // lane within node group
    int node = wave * 4 + sub;
    if (node >= n) return;
    float4 v = x4[(size_t)node * 16 + sl];
    float4 w = w4[sl];
    float t = v.x * w.x + v.y * w.y + v.z * w.z + v.w * w.w;
    t += __shfl_xor(t, 8, 64);
    t += __shfl_xor(t, 4, 64);
    t += __shfl_xor(t, 2, 64);
    t += __shfl_xor(t, 1, 64);
    if (sl == 0) d[node] = t;
}

// ---------------------------------------------------------------------------
// K2: FUSED sumd-scatter + scan1.
//  scatter : sumd[t] += d[s]   (t >= first only).  Algebra:
//            learned[t] = sumd[t] - count[t]*d[t] + (count[t]+1)*lin_b,
//            so the scatter needs NO d[t] read and NO lin_b — those terms
//            are reconstructed coalesced in reorder.
//  scan1   : block-local exclusive scan of count[] -> off[], block sums to
//            partial[].
// ---------------------------------------------------------------------------
__global__ void scatter_scan1_kernel(const int* __restrict__ ei,
                                     const float* __restrict__ d,
                                     float* __restrict__ sumd,
                                     const int* __restrict__ count,
                                     int* __restrict__ off,
                                     int* __restrict__ partial,
                                     int n, int first) {
    __shared__ int sh[256];
    int tid = threadIdx.x;
    int gid = blockIdx.x * 256 + tid;

    // scatter (issue first: atomics drain while the scan runs)
    int t = ei[n + gid];
    if (t >= first) {
        int s = ei[gid];
        atomicAdd(&sumd[t], d[s]);
    }

    // scan1
    int v = count[gid];
    sh[tid] = v;
    __syncthreads();
    for (int o = 1; o < 256; o <<= 1) {
        int tt = (tid >= o) ? sh[tid - o] : 0;
        __syncthreads();
        sh[tid] += tt;
        __syncthreads();
    }
    off[gid] = sh[tid] - v;
    if (tid == 255) partial[blockIdx.x] = sh[255];
}

__global__ void scan2_kernel(int* __restrict__ partial, int nb) {
    __shared__ int sh[256];
    int tid = threadIdx.x;
    int chunk = nb / 256;
    int base = tid * chunk;
    int sum = 0;
    for (int k = 0; k < chunk; ++k) sum += partial[base + k];
    sh[tid] = sum;
    __syncthreads();
    for (int o = 1; o < 256; o <<= 1) {
        int t = (tid >= o) ? sh[tid - o] : 0;
        __syncthreads();
        sh[tid] += t;
        __syncthreads();
    }
    int running = sh[tid] - sum;
    for (int k = 0; k < chunk; ++k) {
        int v = partial[base + k];
        partial[base + k] = running;
        running += v;
    }
}

// ---------------------------------------------------------------------------
// K3: reorder edges into CSR buckets. Positions claimed via atomicAdd on
//  off[] itself (off is its own cursor: post-pass off[t] = local INCLUSIVE
//  prefix, which gather exploits). Score, fully coalesced inputs:
//   e <  first : w1
//   e >= first : (w2|w3 by parity) + sumd[e] - count[e]*d[e]
//                + (count[e]+1)*lin_b
// ---------------------------------------------------------------------------
__global__ void reorder_kernel(const int* __restrict__ ei,
                               const float* __restrict__ sumd,
                               const float* __restrict__ d,
                               const int* __restrict__ count,
                               int* __restrict__ off,
                               const int* __restrict__ partial,
                               int2* __restrict__ srcscore,
                               const float* __restrict__ lin_b,
                               const float* __restrict__ w1,
                               const float* __restrict__ w2,
                               const float* __restrict__ w3,
                               int n, int first) {
    int e = blockIdx.x * blockDim.x + threadIdx.x;
    if (e >= n) return;
    float score;
    if (e < first) {
        score = w1[0];
    } else {
        float base = (((e - first) & 1) == 0) ? w2[0] : w3[0];
        float cnt = (float)count[e];
        score = base + sumd[e] - cnt * d[e] + (cnt + 1.0f) * lin_b[0];
    }
    int s = ei[e];
    int t = ei[n + e];
    int pos = partial[t >> 8] + atomicAdd(&off[t], 1);
    srcscore[pos] = make_int2(s, __float_as_int(score));
}

// ---------------------------------------------------------------------------
// K4: gather (round-2 proven form). Four nodes per wave (16 lanes x float4):
//   out[i,:] = relu(sum_j x[src_j,:]*score_j)
//  - srcscore entries prefetched 16-at-a-time with one coalesced predicated
//    load, then broadcast via __shfl.
//  - out stores NONTEMPORAL: keep x L3-resident for the random row reads.
//  - off[] was consumed as a cursor by reorder: off[t] now holds the local
//    INCLUSIVE prefix, so  beg(t) = partial[t>>8] + (t&255 ? off[t-1] : 0).
// ---------------------------------------------------------------------------
__global__ void gather_kernel(const float4* __restrict__ x4,
                              const int* __restrict__ off,
                              const int* __restrict__ partial,
                              const int2* __restrict__ srcscore,
                              float4* __restrict__ out4, int n) {
    int gtid = blockIdx.x * blockDim.x + threadIdx.x;
    int wave = gtid >> 6;
    int lane = threadIdx.x & 63;
    int sub  = lane >> 4;
    int sl   = lane & 15;
    int node = wave * 4 + sub;
    if (node >= n) return;
    int beg = partial[node >> 8] + ((node & 255) ? off[node - 1] : 0);
    int np1 = node + 1;
    int end = (np1 < n) ? (partial[np1 >> 8] + ((np1 & 255) ? off[node] : 0)) : n;
    float4 acc = make_float4(0.f, 0.f, 0.f, 0.f);
    int base = sub << 4;
    for (int j0 = beg; j0 < end; j0 += 16) {
        int rem = end - j0;
        int m = (rem < 16) ? rem : 16;
        int2 p = make_int2(0, 0);
        if (sl < m) p = srcscore[j0 + sl];      // one coalesced batch load
        for (int k = 0; k < m; ++k) {
            int   src = __shfl(p.x, base + k, 64);
            float s   = __int_as_float(__shfl(p.y, base + k, 64));
            float4 v = x4[(size_t)src * 16 + sl];
            acc.x += v.x * s;
            acc.y += v.y * s;
            acc.z += v.z * s;
            acc.w += v.w * s;
        }
    }
    acc.x = fmaxf(acc.x, 0.f);
    acc.y = fmaxf(acc.y, 0.f);
    acc.z = fmaxf(acc.z, 0.f);
    acc.w = fmaxf(acc.w, 0.f);
    fx4 av;
    av.x = acc.x; av.y = acc.y; av.z = acc.z; av.w = acc.w;
    __builtin_nontemporal_store(av, (fx4*)&out4[(size_t)node * 16 + sl]);
}

extern "C" void kernel_launch(void* const* d_in, const int* in_sizes, int n_in,
                              void* d_out, int out_size, void* d_ws, size_t ws_size,
                              hipStream_t stream) {
    const float* x     = (const float*)d_in[0];   // [N, 64]
    const float* lin_w = (const float*)d_in[1];   // [1, 64]
    const float* lin_b = (const float*)d_in[2];   // [1]
    const float* w1    = (const float*)d_in[3];
    const float* w2    = (const float*)d_in[4];
    const float* w3    = (const float*)d_in[5];
    const int*   ei    = (const int*)d_in[6];     // [2, N]
    float* out = (float*)d_out;                   // [N, 64]

    const int n = in_sizes[0] / C;                // nodes == edges (1048576)
    const int first = n / 3;
    const int nb = n / 256;                       // 4096

    // workspace: 6n ints/floats + nb  (rank[] eliminated; sumd & count
    // adjacent -> one 8 MB memset)
    float* d_dot    = (float*)d_ws;               // n
    float* sumd     = d_dot + n;                  // n
    int*   count    = (int*)(sumd + n);           // n
    int*   off      = count + n;                  // n
    int2*  srcscore = (int2*)(off + n);           // n int2
    int*   partial  = (int*)(srcscore + n);       // nb

    hipMemsetAsync(sumd, 0, (size_t)2 * n * sizeof(int), stream);

    // K1: dot (n/4 waves -> n*16 threads) + degree hist (first n threads)
    dot_hist_kernel<<<dim3(n / 16), dim3(256), 0, stream>>>(
        (const float4*)x, (const float4*)lin_w, ei, d_dot, count, n);
    // K2: sumd scatter + scan1
    scatter_scan1_kernel<<<dim3(nb), dim3(256), 0, stream>>>(
        ei, d_dot, sumd, count, off, partial, n, first);
    scan2_kernel<<<dim3(1), dim3(256), 0, stream>>>(partial, nb);
    reorder_kernel<<<dim3(nb), dim3(256), 0, stream>>>(ei, sumd, d_dot, count,
                                                       off, partial, srcscore,
                                                       lin_b, w1, w2, w3, n, first);
    gather_kernel<<<dim3(n / 16), dim3(256), 0, stream>>>(
        (const float4*)x, off, partial, srcscore, (float4*)out, n);
}